// Round 5
// baseline (971.216 us; speedup 1.0000x reference)
//
#include <hip/hip_runtime.h>
#include <math.h>

// ---- problem constants ----
#define NT   16384
#define HD   4096
#define NE   64
#define TOPK 8

// ---- d_out layout: FLOAT32 elements, concatenated in reference return order ----
// (rounds 2-4 proved the buffer is read as fp32: int outputs are compared as floats)
#define L_OFF 0
#define W_OFF (NT * NE)                  // 1048576
#define I_OFF (W_OFF + NT * TOPK)        // 1179648
#define M_OFF (I_OFF + NT * TOPK)        // 1310720 ; mask = NE*TOPK*NT = 8388608 floats

typedef __attribute__((ext_vector_type(4))) float f4;

// ---- kernel A: zero the fp32 mask region (8388608 floats) ----
__global__ __launch_bounds__(256) void kz_mask(f4* __restrict__ p, int n4) {
  f4 z = {0.f, 0.f, 0.f, 0.f};
  for (int i = blockIdx.x * 256 + threadIdx.x; i < n4; i += gridDim.x * 256) p[i] = z;
}

// ---- kernel B: whole router, single safe path ----
// one wave handles 4 tokens; lane = expert. Pure fp32 dot, no LDS, no MFMA.
#define TPW 4
__global__ __launch_bounds__(256) void kr_probe(const float* __restrict__ x,
                                                const float* __restrict__ w,
                                                const float* __restrict__ bias,
                                                float* __restrict__ out) {
  const int lane = threadIdx.x & 63;
  const int wv   = threadIdx.x >> 6;
  const int t0   = (blockIdx.x * 4 + wv) * TPW;     // 1024 blocks * 4 waves * 4 tokens = 16384

  const float* wp = w + (size_t)lane * HD;          // this lane's expert row (L2-resident, 1 MB)

  f4 acc[TPW];
#pragma unroll
  for (int j = 0; j < TPW; ++j) acc[j] = (f4){0.f, 0.f, 0.f, 0.f};

  for (int it = 0; it < HD / 4; ++it) {
    f4 wv4 = *(const f4*)(wp + it * 4);
#pragma unroll
    for (int j = 0; j < TPW; ++j) {
      f4 xv = *(const f4*)(x + (size_t)(t0 + j) * HD + it * 4);  // wave-uniform row
      acc[j] = (f4){fmaf(xv[0], wv4[0], acc[j][0]),
                    fmaf(xv[1], wv4[1], acc[j][1]),
                    fmaf(xv[2], wv4[2], acc[j][2]),
                    fmaf(xv[3], wv4[3], acc[j][3])};
    }
  }

#pragma unroll
  for (int j = 0; j < TPW; ++j) {
    const int t = t0 + j;
    float v = acc[j][0] + acc[j][1] + acc[j][2] + acc[j][3] + bias[lane];

    // logits (fp32)
    out[L_OFF + (size_t)t * NE + lane] = v;

    // rank of this lane's logit: #{e : v_e > v or (v_e == v and e < lane)}  (stable, lax.top_k order)
    int rank = 0;
    for (int e = 0; e < NE; ++e) {
      float ve = __shfl(v, e);
      rank += (ve > v) || (ve == v && e < lane);
    }

    // weights = softmax over the selected 8 (global Z cancels in the renormalization)
    float m0 = v;
#pragma unroll
    for (int o = 32; o; o >>= 1) m0 = fmaxf(m0, __shfl_xor(m0, o));
    float ev = (rank < TOPK) ? expf(v - m0) : 0.f;
    float s = ev;
#pragma unroll
    for (int o = 32; o; o >>= 1) s += __shfl_xor(s, o);

    if (rank < TOPK) {
      out[W_OFF + (size_t)t * TOPK + rank] = ev / s;          // fp32 weight
      out[I_OFF + (size_t)t * TOPK + rank] = (float)lane;     // index as float (exact <= 63)
      out[M_OFF + ((size_t)lane * TOPK + rank) * NT + t] = 1.0f;  // mask one-hot
    }
  }
}

extern "C" void kernel_launch(void* const* d_in, const int* in_sizes, int n_in,
                              void* d_out, int out_size, void* d_ws, size_t ws_size,
                              hipStream_t stream) {
  const float* x  = (const float*)d_in[0];
  const float* gw = (const float*)d_in[1];
  const float* gb = (const float*)d_in[2];
  float* out = (float*)d_out;

  kz_mask <<<2048, 256, 0, stream>>>((f4*)(out + M_OFF), (NE * TOPK * NT) / 4);
  kr_probe<<<1024, 256, 0, stream>>>(x, gw, gb, out);
}

// Round 7
// 240.729 us; speedup vs baseline: 4.0345x; 4.0345x over previous
//
#include <hip/hip_runtime.h>
#include <math.h>

// ---- problem constants ----
#define NT   16384
#define HD   4096
#define NE   64
#define TOPK 8

// ---- d_out layout: FLOAT32 elements (proven round 5) ----
#define L_OFF 0
#define W_OFF (NT * NE)                  // 1048576
#define I_OFF (W_OFF + NT * TOPK)        // 1179648
#define M_OFF (I_OFF + NT * TOPK)        // 1310720 ; mask = NE*TOPK*NT floats

#define BK 64                            // K-chunk

typedef __attribute__((ext_vector_type(4))) float f4;

// ---- kernel A: zero the fp32 mask region ----
__global__ __launch_bounds__(256) void kz_mask(f4* __restrict__ p, int n4) {
  f4 z = {0.f, 0.f, 0.f, 0.f};
  for (int i = blockIdx.x * 256 + threadIdx.x; i < n4; i += gridDim.x * 256) p[i] = z;
}

// ---- kernel B: tiled fp32 VALU GEMM, bitwise-identical accumulation to round 5 ----
// block: 512 thr (8 waves) = 64 tokens (lane=token) x 64 experts (8 per wave, wave-uniform)
__global__ __launch_bounds__(512) void k_gemm(const float* __restrict__ x,
                                              const float* __restrict__ w,
                                              const float* __restrict__ bias,
                                              float* __restrict__ out) {
  __shared__ float xs[64 * 65];          // stride 65: bank = row%32 -> 2-way (free)
  __shared__ float ws[64 * 64];          // linear: reads are wave-uniform broadcasts

  const int tid  = threadIdx.x;
  const int lane = tid & 63;             // token within tile
  const int wv   = tid >> 6;             // 0..7 -> experts wv*8..wv*8+7
  const int tok0 = blockIdx.x * 64;

  f4 acc[8];
#pragma unroll
  for (int s = 0; s < 8; ++s) acc[s] = (f4){0.f, 0.f, 0.f, 0.f};

  // unit P (0..1023): row = P>>4, u = P&15 ; this thread owns P0=tid, P1=tid+512
  const int r0 = tid >> 4,          u0 = tid & 15;
  const int r1 = (tid + 512) >> 4,  u1 = tid & 15;   // (tid+512)&15 == tid&15

  // prefetch chunk 0 into registers
  f4 xr0 = *(const f4*)(x + (size_t)(tok0 + r0) * HD + u0 * 4);
  f4 xr1 = *(const f4*)(x + (size_t)(tok0 + r1) * HD + u1 * 4);
  f4 wr0 = *(const f4*)(w + (size_t)r0 * HD + u0 * 4);
  f4 wr1 = *(const f4*)(w + (size_t)r1 * HD + u1 * 4);

  for (int c = 0; c < HD / BK; ++c) {
    __syncthreads();                     // all waves done reading previous chunk

    // LDS writes from prefetch regs (compiler inserts vmcnt waits on the deps)
#pragma unroll
    for (int j = 0; j < 4; ++j) xs[r0 * 65 + u0 * 4 + j] = xr0[j];
#pragma unroll
    for (int j = 0; j < 4; ++j) xs[r1 * 65 + u1 * 4 + j] = xr1[j];
    *(f4*)(ws + r0 * 64 + u0 * 4) = wr0;
    *(f4*)(ws + r1 * 64 + u1 * 4) = wr1;

    // issue next chunk's global loads now; they complete under this chunk's compute
    if (c + 1 < HD / BK) {
      const int kc = (c + 1) * BK;
      xr0 = *(const f4*)(x + (size_t)(tok0 + r0) * HD + kc + u0 * 4);
      xr1 = *(const f4*)(x + (size_t)(tok0 + r1) * HD + kc + u1 * 4);
      wr0 = *(const f4*)(w + (size_t)r0 * HD + kc + u0 * 4);
      wr1 = *(const f4*)(w + (size_t)r1 * HD + kc + u1 * 4);
    }

    __syncthreads();                     // staged chunk visible

    // compute: k ascending, f4-component chains — round-5 fp order exactly
#pragma unroll
    for (int st = 0; st < 16; ++st) {
      const int k0 = st * 4;
      const float x0 = xs[lane * 65 + k0 + 0];
      const float x1 = xs[lane * 65 + k0 + 1];
      const float x2 = xs[lane * 65 + k0 + 2];
      const float x3 = xs[lane * 65 + k0 + 3];
#pragma unroll
      for (int s = 0; s < 8; ++s) {
        f4 wf = *(const f4*)(ws + (wv * 8 + s) * 64 + k0);   // wave-uniform broadcast
        acc[s][0] = fmaf(x0, wf[0], acc[s][0]);
        acc[s][1] = fmaf(x1, wf[1], acc[s][1]);
        acc[s][2] = fmaf(x2, wf[2], acc[s][2]);
        acc[s][3] = fmaf(x3, wf[3], acc[s][3]);
      }
    }
  }

  // epilogue: same final-sum order as round 5: ((c0+c1)+c2)+c3 + bias
#pragma unroll
  for (int s = 0; s < 8; ++s) {
    const int e = wv * 8 + s;
    float v = acc[s][0] + acc[s][1] + acc[s][2] + acc[s][3] + bias[e];
    out[L_OFF + (size_t)(tok0 + lane) * NE + e] = v;
  }
}

// ---- kernel C: top-8 from stored fp32 logits (round-5-verbatim selection) ----
__global__ __launch_bounds__(256) void k_topk(float* __restrict__ out) {
  const int lane = threadIdx.x & 63;            // lane == expert
  const int wv   = threadIdx.x >> 6;
  const int t    = blockIdx.x * 4 + wv;

  float v = out[L_OFF + (size_t)t * NE + lane];

  // rank = #{e : v_e > v or (v_e == v and e < lane)}  (stable, lax.top_k order)
  int rank = 0;
  for (int e = 0; e < NE; ++e) {
    float ve = __shfl(v, e);
    rank += (ve > v) || (ve == v && e < lane);
  }

  // weights = softmax over the selected 8 (global Z cancels in renormalization)
  float m0 = v;
#pragma unroll
  for (int o = 32; o; o >>= 1) m0 = fmaxf(m0, __shfl_xor(m0, o));
  float ev = (rank < TOPK) ? expf(v - m0) : 0.f;
  float s = ev;
#pragma unroll
  for (int o = 32; o; o >>= 1) s += __shfl_xor(s, o);

  if (rank < TOPK) {
    out[W_OFF + (size_t)t * TOPK + rank] = ev / s;
    out[I_OFF + (size_t)t * TOPK + rank] = (float)lane;                  // exact (<=63)
    out[M_OFF + ((size_t)lane * TOPK + rank) * NT + t] = 1.0f;           // mask one-hot
  }
}

extern "C" void kernel_launch(void* const* d_in, const int* in_sizes, int n_in,
                              void* d_out, int out_size, void* d_ws, size_t ws_size,
                              hipStream_t stream) {
  const float* x  = (const float*)d_in[0];
  const float* gw = (const float*)d_in[1];
  const float* gb = (const float*)d_in[2];
  float* out = (float*)d_out;

  kz_mask<<<2048, 256, 0, stream>>>((f4*)(out + M_OFF), (NE * TOPK * NT) / 4);
  k_gemm <<<NT / 64, 512, 0, stream>>>(x, gw, gb, out);
  k_topk <<<NT / 4, 256, 0, stream>>>(out);
}

// Round 8
// 212.033 us; speedup vs baseline: 4.5805x; 1.1353x over previous
//
#include <hip/hip_runtime.h>
#include <math.h>

// ---- problem constants ----
#define NT   16384
#define HD   4096
#define NE   64
#define TOPK 8

// ---- d_out layout: FLOAT32 elements (proven round 5/7) ----
#define L_OFF 0
#define W_OFF (NT * NE)                  // 1048576
#define I_OFF (W_OFF + NT * TOPK)        // 1179648
#define M_OFF (I_OFF + NT * TOPK)        // 1310720 ; mask = NE*TOPK*NT floats

#define BK  64                           // K-chunk
#define XS_STRIDE 66                     // conflict-free x reads (bank = 4tg+2i+4st)
#define WS_STRIDE 68                     // conflict-free w reads (bank = 4eg+4st)

typedef __attribute__((ext_vector_type(4))) float f4;

// ---- kernel A: zero the fp32 mask region ----
__global__ __launch_bounds__(256) void kz_mask(f4* __restrict__ p, int n4) {
  f4 z = {0.f, 0.f, 0.f, 0.f};
  for (int i = blockIdx.x * 256 + threadIdx.x; i < n4; i += gridDim.x * 256) p[i] = z;
}

// ---- kernel B: register-tiled fp32 VALU GEMM ----
// block 256 thr (4 waves) = tile 32 tokens x 64 experts; grid NT/32 = 512 (2 blocks/CU)
// wave (wt,we) covers 16 tokens x 32 experts; lane (tg,eg) 8x8; thread: 2 tokens x 4 experts.
// Accumulation is BITWISE-IDENTICAL to the round-5/7 pass: per (t,e), 4 component
// chains (k mod 4), k ascending, final ((c0+c1)+c2)+c3 + bias.
__global__ __launch_bounds__(256, 4) void k_gemm(const float* __restrict__ x,
                                                 const float* __restrict__ w,
                                                 const float* __restrict__ bias,
                                                 float* __restrict__ out) {
  __shared__ float xs[32 * XS_STRIDE];   // 8.4 KB
  __shared__ float ws[64 * WS_STRIDE];   // 17.4 KB

  const int tid  = threadIdx.x;
  const int lane = tid & 63;
  const int wv   = tid >> 6;
  const int wt   = wv >> 1;              // token half: rows wt*16..+15
  const int we   = wv & 1;               // expert half: experts we*32..+31
  const int tg   = lane >> 3;
  const int eg   = lane & 7;
  const int tok0 = blockIdx.x * 32;

  f4 acc[2][4];
#pragma unroll
  for (int i = 0; i < 2; ++i)
#pragma unroll
    for (int s = 0; s < 4; ++s) acc[i][s] = (f4){0.f, 0.f, 0.f, 0.f};

  // staging ownership: unit P -> row P>>4, 16B-unit P&15
  const int sr = tid >> 4;               // 0..15
  const int su = tid & 15;

  // prefetch chunk 0 into registers (x: 2 units, w: 4 units per thread)
  f4 xr0 = *(const f4*)(x + (size_t)(tok0 + sr) * HD + su * 4);
  f4 xr1 = *(const f4*)(x + (size_t)(tok0 + 16 + sr) * HD + su * 4);
  f4 wr[4];
#pragma unroll
  for (int p = 0; p < 4; ++p)
    wr[p] = *(const f4*)(w + (size_t)(sr + 16 * p) * HD + su * 4);

  for (int c = 0; c < HD / BK; ++c) {
    __syncthreads();                     // all waves done reading previous chunk

    *(f4*)(xs + sr * XS_STRIDE + su * 4)        = xr0;
    *(f4*)(xs + (16 + sr) * XS_STRIDE + su * 4) = xr1;
#pragma unroll
    for (int p = 0; p < 4; ++p)
      *(f4*)(ws + (sr + 16 * p) * WS_STRIDE + su * 4) = wr[p];

    // issue next chunk's global loads; they complete under this chunk's compute
    if (c + 1 < HD / BK) {
      const int kc = (c + 1) * BK;
      xr0 = *(const f4*)(x + (size_t)(tok0 + sr) * HD + kc + su * 4);
      xr1 = *(const f4*)(x + (size_t)(tok0 + 16 + sr) * HD + kc + su * 4);
#pragma unroll
      for (int p = 0; p < 4; ++p)
        wr[p] = *(const f4*)(w + (size_t)(sr + 16 * p) * HD + kc + su * 4);
    }

    __syncthreads();                     // staged chunk visible

#pragma unroll
    for (int st = 0; st < 16; ++st) {
      const int k0 = st * 4;
      f4 xv0 = *(const f4*)(xs + (wt * 16 + tg * 2 + 0) * XS_STRIDE + k0);
      f4 xv1 = *(const f4*)(xs + (wt * 16 + tg * 2 + 1) * XS_STRIDE + k0);
      f4 wf[4];
#pragma unroll
      for (int s = 0; s < 4; ++s)
        wf[s] = *(const f4*)(ws + (we * 32 + eg + 8 * s) * WS_STRIDE + k0);
#pragma unroll
      for (int s = 0; s < 4; ++s) {
#pragma unroll
        for (int j = 0; j < 4; ++j) {
          acc[0][s][j] = fmaf(xv0[j], wf[s][j], acc[0][s][j]);
          acc[1][s][j] = fmaf(xv1[j], wf[s][j], acc[1][s][j]);
        }
      }
    }
  }

  // epilogue: same final-sum order as rounds 5/7
#pragma unroll
  for (int i = 0; i < 2; ++i) {
    const int row = tok0 + wt * 16 + tg * 2 + i;
#pragma unroll
    for (int s = 0; s < 4; ++s) {
      const int e = we * 32 + eg + 8 * s;
      float v = acc[i][s][0] + acc[i][s][1] + acc[i][s][2] + acc[i][s][3] + bias[e];
      out[L_OFF + (size_t)row * NE + e] = v;
    }
  }
}

// ---- kernel C: top-8 from stored fp32 logits (round-5/7-verbatim selection) ----
__global__ __launch_bounds__(256) void k_topk(float* __restrict__ out) {
  const int lane = threadIdx.x & 63;            // lane == expert
  const int wv   = threadIdx.x >> 6;
  const int t    = blockIdx.x * 4 + wv;

  float v = out[L_OFF + (size_t)t * NE + lane];

  // rank = #{e : v_e > v or (v_e == v and e < lane)}  (stable, lax.top_k order)
  int rank = 0;
  for (int e = 0; e < NE; ++e) {
    float ve = __shfl(v, e);
    rank += (ve > v) || (ve == v && e < lane);
  }

  // weights = softmax over the selected 8 (global Z cancels in renormalization)
  float m0 = v;
#pragma unroll
  for (int o = 32; o; o >>= 1) m0 = fmaxf(m0, __shfl_xor(m0, o));
  float ev = (rank < TOPK) ? expf(v - m0) : 0.f;
  float s = ev;
#pragma unroll
  for (int o = 32; o; o >>= 1) s += __shfl_xor(s, o);

  if (rank < TOPK) {
    out[W_OFF + (size_t)t * TOPK + rank] = ev / s;
    out[I_OFF + (size_t)t * TOPK + rank] = (float)lane;                  // exact (<=63)
    out[M_OFF + ((size_t)lane * TOPK + rank) * NT + t] = 1.0f;           // mask one-hot
  }
}

extern "C" void kernel_launch(void* const* d_in, const int* in_sizes, int n_in,
                              void* d_out, int out_size, void* d_ws, size_t ws_size,
                              hipStream_t stream) {
  const float* x  = (const float*)d_in[0];
  const float* gw = (const float*)d_in[1];
  const float* gb = (const float*)d_in[2];
  float* out = (float*)d_out;

  kz_mask<<<2048, 256, 0, stream>>>((f4*)(out + M_OFF), (NE * TOPK * NT) / 4);
  k_gemm <<<NT / 32, 256, 0, stream>>>(x, gw, gb, out);
  k_topk <<<NT / 4, 256, 0, stream>>>(out);
}

// Round 9
// 186.364 us; speedup vs baseline: 5.2114x; 1.1377x over previous
//
#include <hip/hip_runtime.h>
#include <math.h>

// ---- problem constants ----
#define NT   16384
#define HD   4096
#define NE   64
#define TOPK 8

// ---- d_out layout: FLOAT32 elements (proven rounds 5/7/8) ----
#define L_OFF 0
#define W_OFF (NT * NE)                  // 1048576
#define I_OFF (W_OFF + NT * TOPK)        // 1179648
#define M_OFF (I_OFF + NT * TOPK)        // 1310720 ; mask = NE*TOPK*NT floats

#define BK  64                           // K-chunk
#define XS_STRIDE 66
#define WS_STRIDE 68

typedef __attribute__((ext_vector_type(4))) float f4;

// ---- kernel A: zero the fp32 mask region ----
__global__ __launch_bounds__(256) void kz_mask(f4* __restrict__ p, int n4) {
  f4 z = {0.f, 0.f, 0.f, 0.f};
  for (int i = blockIdx.x * 256 + threadIdx.x; i < n4; i += gridDim.x * 256) p[i] = z;
}

// ---- kernel B: register-tiled fp32 VALU GEMM, double-buffered LDS pipeline ----
// block 256 thr (4 waves) = tile 32 tokens x 64 experts; grid NT/32 = 512
// thread: 2 tokens x 4 experts. Per-(t,e) accumulation BITWISE-IDENTICAL to
// rounds 5/7/8: 4 component chains (k mod 4), k ascending, ((c0+c1)+c2)+c3 + bias.
// Pipeline: compute chunk c from buf[c&1] while ds-writing chunk c+1 (regs landed)
// to buf[(c+1)&1] and issuing global loads for chunk c+2. One barrier per chunk.
__global__ __launch_bounds__(256, 2) void k_gemm(const float* __restrict__ x,
                                                 const float* __restrict__ w,
                                                 const float* __restrict__ bias,
                                                 float* __restrict__ out) {
  __shared__ float xs[2][32 * XS_STRIDE];   // 2 x 8.4 KB
  __shared__ float ws[2][64 * WS_STRIDE];   // 2 x 17.4 KB

  const int tid  = threadIdx.x;
  const int lane = tid & 63;
  const int wv   = tid >> 6;
  const int wt   = wv >> 1;              // token half: rows wt*16..+15
  const int we   = wv & 1;               // expert half: experts we*32..+31
  const int tg   = lane >> 3;
  const int eg   = lane & 7;
  const int tok0 = blockIdx.x * 32;

  f4 acc[2][4];
#pragma unroll
  for (int i = 0; i < 2; ++i)
#pragma unroll
    for (int s = 0; s < 4; ++s) acc[i][s] = (f4){0.f, 0.f, 0.f, 0.f};

  // staging ownership: row sr (and +16 / +16p), 16B-unit su
  const int sr = tid >> 4;               // 0..15
  const int su = tid & 15;

  const float* xb0 = x + (size_t)(tok0 + sr) * HD + su * 4;
  const float* xb1 = x + (size_t)(tok0 + 16 + sr) * HD + su * 4;
  const float* wb0 = w + (size_t)(sr +  0) * HD + su * 4;
  const float* wb1 = w + (size_t)(sr + 16) * HD + su * 4;
  const float* wb2 = w + (size_t)(sr + 32) * HD + su * 4;
  const float* wb3 = w + (size_t)(sr + 48) * HD + su * 4;

#define LOADSET(X0, X1, W0, W1, W2, W3, c)            \
  do { const int kc_ = (c) * BK;                      \
    X0 = *(const f4*)(xb0 + kc_);                     \
    X1 = *(const f4*)(xb1 + kc_);                     \
    W0 = *(const f4*)(wb0 + kc_);                     \
    W1 = *(const f4*)(wb1 + kc_);                     \
    W2 = *(const f4*)(wb2 + kc_);                     \
    W3 = *(const f4*)(wb3 + kc_);                     \
  } while (0)

#define WRITESET(b, X0, X1, W0, W1, W2, W3)                    \
  do {                                                         \
    *(f4*)(&xs[b][sr * XS_STRIDE + su * 4])        = X0;       \
    *(f4*)(&xs[b][(16 + sr) * XS_STRIDE + su * 4]) = X1;       \
    *(f4*)(&ws[b][(sr +  0) * WS_STRIDE + su * 4]) = W0;       \
    *(f4*)(&ws[b][(sr + 16) * WS_STRIDE + su * 4]) = W1;       \
    *(f4*)(&ws[b][(sr + 32) * WS_STRIDE + su * 4]) = W2;       \
    *(f4*)(&ws[b][(sr + 48) * WS_STRIDE + su * 4]) = W3;       \
  } while (0)

#define COMPUTE(b)                                                         \
  do {                                                                     \
    _Pragma("unroll")                                                      \
    for (int st = 0; st < 16; ++st) {                                      \
      const int k0 = st * 4;                                               \
      f4 xv0 = *(const f4*)(&xs[b][(wt * 16 + tg * 2 + 0) * XS_STRIDE + k0]); \
      f4 xv1 = *(const f4*)(&xs[b][(wt * 16 + tg * 2 + 1) * XS_STRIDE + k0]); \
      f4 wf0 = *(const f4*)(&ws[b][(we * 32 + eg +  0) * WS_STRIDE + k0]); \
      f4 wf1 = *(const f4*)(&ws[b][(we * 32 + eg +  8) * WS_STRIDE + k0]); \
      f4 wf2 = *(const f4*)(&ws[b][(we * 32 + eg + 16) * WS_STRIDE + k0]); \
      f4 wf3 = *(const f4*)(&ws[b][(we * 32 + eg + 24) * WS_STRIDE + k0]); \
      _Pragma("unroll")                                                    \
      for (int j = 0; j < 4; ++j) {                                        \
        acc[0][0][j] = fmaf(xv0[j], wf0[j], acc[0][0][j]);                 \
        acc[1][0][j] = fmaf(xv1[j], wf0[j], acc[1][0][j]);                 \
        acc[0][1][j] = fmaf(xv0[j], wf1[j], acc[0][1][j]);                 \
        acc[1][1][j] = fmaf(xv1[j], wf1[j], acc[1][1][j]);                 \
        acc[0][2][j] = fmaf(xv0[j], wf2[j], acc[0][2][j]);                 \
        acc[1][2][j] = fmaf(xv1[j], wf2[j], acc[1][2][j]);                 \
        acc[0][3][j] = fmaf(xv0[j], wf3[j], acc[0][3][j]);                 \
        acc[1][3][j] = fmaf(xv1[j], wf3[j], acc[1][3][j]);                 \
      }                                                                    \
    }                                                                      \
  } while (0)

  f4 xA0, xA1, wA0, wA1, wA2, wA3;
  f4 xB0, xB1, wB0, wB1, wB2, wB3;

  // prologue: chunk0 -> regsA -> buf0; chunk1 -> regsB (in flight)
  LOADSET(xA0, xA1, wA0, wA1, wA2, wA3, 0);
  LOADSET(xB0, xB1, wB0, wB1, wB2, wB3, 1);
  WRITESET(0, xA0, xA1, wA0, wA1, wA2, wA3);
  __syncthreads();

  for (int cc = 0; cc < 62; cc += 2) {
    // even chunk cc: compute buf0; stage chunk cc+1 -> buf1; load chunk cc+2 -> A
    WRITESET(1, xB0, xB1, wB0, wB1, wB2, wB3);
    LOADSET(xA0, xA1, wA0, wA1, wA2, wA3, cc + 2);
    COMPUTE(0);
    __syncthreads();
    // odd chunk cc+1: compute buf1; stage chunk cc+2 -> buf0; load chunk cc+3 -> B
    WRITESET(0, xA0, xA1, wA0, wA1, wA2, wA3);
    LOADSET(xB0, xB1, wB0, wB1, wB2, wB3, cc + 3);
    COMPUTE(1);
    __syncthreads();
  }
  // chunks 62 (in buf0) and 63 (regsB -> buf1)
  WRITESET(1, xB0, xB1, wB0, wB1, wB2, wB3);
  COMPUTE(0);
  __syncthreads();
  COMPUTE(1);

  // epilogue: same final-sum order as rounds 5/7/8
#pragma unroll
  for (int i = 0; i < 2; ++i) {
    const int row = tok0 + wt * 16 + tg * 2 + i;
#pragma unroll
    for (int s = 0; s < 4; ++s) {
      const int e = we * 32 + eg + 8 * s;
      float v = acc[i][s][0] + acc[i][s][1] + acc[i][s][2] + acc[i][s][3] + bias[e];
      out[L_OFF + (size_t)row * NE + e] = v;
    }
  }
#undef LOADSET
#undef WRITESET
#undef COMPUTE
}

// ---- kernel C: top-8 from stored fp32 logits (round-5/7/8-verbatim selection) ----
__global__ __launch_bounds__(256) void k_topk(float* __restrict__ out) {
  const int lane = threadIdx.x & 63;            // lane == expert
  const int wv   = threadIdx.x >> 6;
  const int t    = blockIdx.x * 4 + wv;

  float v = out[L_OFF + (size_t)t * NE + lane];

  // rank = #{e : v_e > v or (v_e == v and e < lane)}  (stable, lax.top_k order)
  int rank = 0;
  for (int e = 0; e < NE; ++e) {
    float ve = __shfl(v, e);
    rank += (ve > v) || (ve == v && e < lane);
  }

  // weights = softmax over the selected 8 (global Z cancels in renormalization)
  float m0 = v;
#pragma unroll
  for (int o = 32; o; o >>= 1) m0 = fmaxf(m0, __shfl_xor(m0, o));
  float ev = (rank < TOPK) ? expf(v - m0) : 0.f;
  float s = ev;
#pragma unroll
  for (int o = 32; o; o >>= 1) s += __shfl_xor(s, o);

  if (rank < TOPK) {
    out[W_OFF + (size_t)t * TOPK + rank] = ev / s;
    out[I_OFF + (size_t)t * TOPK + rank] = (float)lane;                  // exact (<=63)
    out[M_OFF + ((size_t)lane * TOPK + rank) * NT + t] = 1.0f;           // mask one-hot
  }
}

extern "C" void kernel_launch(void* const* d_in, const int* in_sizes, int n_in,
                              void* d_out, int out_size, void* d_ws, size_t ws_size,
                              hipStream_t stream) {
  const float* x  = (const float*)d_in[0];
  const float* gw = (const float*)d_in[1];
  const float* gb = (const float*)d_in[2];
  float* out = (float*)d_out;

  kz_mask<<<2048, 256, 0, stream>>>((f4*)(out + M_OFF), (NE * TOPK * NT) / 4);
  k_gemm <<<NT / 32, 256, 0, stream>>>(x, gw, gb, out);
  k_topk <<<NT / 4, 256, 0, stream>>>(out);
}